// Round 10
// baseline (139.704 us; speedup 1.0000x reference)
//
#include <hip/hip_runtime.h>

// WaveletLinear: y[b,o] = sum_i w[o,i] * (1 - s^2) * exp(-0.5 s^2),
//   s = (x[b,i] - t[o,i]) / (A_MIN + softplus(sr[o,i]) + EPS)
// Rework: s' = s*sqrt(K), K = 0.5*log2(e); u = s'^2 = K*s^2; e2 = exp2(-u)
//   = exp(-s^2/2); (1 - s^2) = 1 - u/K;  y = sum_i w * (1 - u/K) * e2.
//
// R15 == R14 resubmitted verbatim (round 9 died to a container-acquisition
// infra failure; no bench signal was produced; kernel audits hang-free).
//
// R14: structural latency fix -- INVERT the lane mapping (lane = b, not o).
// R11-R13 evidence: pipes ~2/3 idle (wall 440 cyc/wave-step vs ~190 busy);
// per-step JIT global param loads stall all 8 phase-locked waves; hipcc
// refuses a register pipeline (R12/R13 both spilled to scratch). With
// lane=b, params are wave-UNIFORM -> staged once per 32-i chunk into LDS by
// a coalesced float4 copy (prep emits a block-chunk-contiguous layout), and
// x sits in 32 registers per lane (reloaded per chunk from an LDS
// transpose). Inner loop touches only LDS-broadcast float4s with 8-way ILP.
// No per-step global loads exist at all. Cost: w varies per elem -> 5
// VALU/elem (floor 13.7 -> 17.1 us) traded against ~20 us of stall.
// Geometry: grid (64 o-blk, 8 b-tiles) = 512 blocks (2/CU, anti-phase
// covers the single-buffered stage), 512 thr = 8 waves; wave = 64 b x 2 o;
// 16 chunks x 32 i. LDS 8 KB xT + 6 KB params.

#define WL_A_MIN 0.001f
#define WL_EPS   1e-8f

constexpr int WL_B = 512;
constexpr int WL_O = 1024;
constexpr int WL_I = 512;

// K = 0.5*log2(e); sqrt(K); 1/K; log2(e); ln(2)
#define WL_SQK  0.84932180553704583800f
#define WL_IK   1.38629436111989061883f
#define WL_L2E  1.44269504088896340736f
#define WL_LN2  0.69314718055994530942f

__device__ __forceinline__ float fast_exp2(float a) {
#if __has_builtin(__builtin_amdgcn_exp2f)
    return __builtin_amdgcn_exp2f(a);
#else
    return exp2f(a);
#endif
}
__device__ __forceinline__ float fast_log2(float a) {
#if __has_builtin(__builtin_amdgcn_logf)
    return __builtin_amdgcn_logf(a);
#else
    return __log2f(a);
#endif
}
__device__ __forceinline__ float fast_rcp(float a) {
#if __has_builtin(__builtin_amdgcn_rcpf)
    return __builtin_amdgcn_rcpf(a);
#else
    return 1.0f / a;
#endif
}

// one element: 5 VALU + 1 trans.  h = 1 - u/K = 1 - s^2 (exact form)
__device__ __forceinline__ void wl_elem(float nti, float inv, float w,
                                        float xv, float& acc) {
    const float s = fmaf(xv, inv, nti);
    const float u = s * s;
    const float e = fast_exp2(-u);                 // exp(-s^2/2)
    const float h = fmaf(-WL_IK, u, 1.0f);         // 1 - s^2 (const inline)
    acc = fmaf(w * h, e, acc);
}

// one quarter: 8 elems of one o from 6 uniform float4 LDS reads.
// Pl layout: [o_l][i_l][3] floats -> o_l row = 24 float4; quarter = 6 float4.
#define WL_Q(ACC, OSEL, Q)                                                    \
  {                                                                           \
    const float4* P4_ = reinterpret_cast<const float4*>(Pl);                  \
    const int bse_ = (wid * 2 + (OSEL)) * 24 + (Q) * 6;                       \
    const float4 a0 = P4_[bse_ + 0], a1 = P4_[bse_ + 1], a2 = P4_[bse_ + 2];  \
    const float4 a3 = P4_[bse_ + 3], a4 = P4_[bse_ + 4], a5 = P4_[bse_ + 5];  \
    wl_elem(a0.x, a0.y, a0.z, xr[(Q) * 8 + 0], ACC);                          \
    wl_elem(a0.w, a1.x, a1.y, xr[(Q) * 8 + 1], ACC);                          \
    wl_elem(a1.z, a1.w, a2.x, xr[(Q) * 8 + 2], ACC);                          \
    wl_elem(a2.y, a2.z, a2.w, xr[(Q) * 8 + 3], ACC);                          \
    wl_elem(a3.x, a3.y, a3.z, xr[(Q) * 8 + 4], ACC);                          \
    wl_elem(a3.w, a4.x, a4.y, xr[(Q) * 8 + 5], ACC);                          \
    wl_elem(a4.z, a4.w, a5.x, xr[(Q) * 8 + 6], ACC);                          \
    wl_elem(a5.y, a5.z, a5.w, xr[(Q) * 8 + 7], ACC);                          \
  }

// Param precompute -> block-chunk-contiguous layout:
//   P[gx][c][o_l][i_l][3],  gx = o>>4 (o-block of 16), c = i>>5 (chunk of 32),
//   o_l = o&15, i_l = i&31.  Each (gx,c) slab = 1536 contiguous floats (6 KB)
//   = exactly what one wl_main block stages per chunk with one float4 copy.
// Read side identical to the verified R10 prep (coalesced float4, o-major).
__global__ __launch_bounds__(256) void wl_prep(
    const float* __restrict__ translation,
    const float* __restrict__ scale_raw,
    const float* __restrict__ weights,
    float* __restrict__ P)
{
    const int t   = threadIdx.x;
    const int o   = blockIdx.x * 64 + (t >> 2);        // 64 o per block
    const int i0  = blockIdx.y * 16 + (t & 3) * 4;     // 16 i per block
    const size_t g = (size_t)o * WL_I + i0;
    const float4 tv = *reinterpret_cast<const float4*>(translation + g);
    const float4 sv = *reinterpret_cast<const float4*>(scale_raw   + g);
    const float4 wv = *reinterpret_cast<const float4*>(weights     + g);
    const float tt[4] = {tv.x, tv.y, tv.z, tv.w};
    const float ss[4] = {sv.x, sv.y, sv.z, sv.w};
    const float ww[4] = {wv.x, wv.y, wv.z, wv.w};
    const int gx = o >> 4, o_l = o & 15;
    #pragma unroll
    for (int j = 0; j < 4; ++j) {
        const int i  = i0 + j;
        const int c  = i >> 5, i_l = i & 31;
        const float ex  = fast_exp2(ss[j] * WL_L2E);   // softplus via hw exp2/log2
        const float sp  = fast_log2(1.0f + ex) * WL_LN2;
        const float inv = fast_rcp(WL_A_MIN + sp + WL_EPS) * WL_SQK;
        const size_t off = ((((size_t)gx * 16 + c) * 16 + o_l) * 32 + i_l) * 3;
        P[off + 0] = -tt[j] * inv;                     // nti
        P[off + 1] = inv;
        P[off + 2] = ww[j];
    }
}

// Main: grid (64, 8) = 512 blocks (2/CU), 512 thr = 8 waves (4/SIMD).
// lane = b (64 b per block row-tile), wave wid owns o = gx*16 + wid*2 +{0,1}.
// Per chunk c (32 i): coop-stage params slab (6 KB) + xT (8 KB), then pure
// register/LDS-broadcast compute. Linear block id = gy*64+gx -> XCD = gx%8:
// all 8 b-tiles sharing a param slab land on one XCD (slab L2-resident).
__global__ __launch_bounds__(512, 4) void wl_main(
    const float* __restrict__ x,
    const float* __restrict__ P,
    float* __restrict__ out)
{
    __shared__ float xT[32 * 64];                      // 8 KB  [i_l][b_l]
    __shared__ float Pl[16 * 32 * 3];                  // 6 KB  [o_l][i_l][3]

    const int tid  = threadIdx.x;
    const int lane = tid & 63;                         // = b_l
    const int wid  = tid >> 6;                         // 0..7
    const int gx   = blockIdx.x;                       // o-block (16 o)
    const int gy   = blockIdx.y;                       // b-tile  (64 b)
    const float* __restrict__ Pg = P + (size_t)gx * (16 * 512 * 3);

    float acc0 = 0.f, acc1 = 0.f;
    float xr[32];

    for (int c = 0; c < 16; ++c) {
        __syncthreads();                               // prev chunk readers done
        // ---- stage params: one contiguous 6 KB slab, 384 float4 ----
        if (tid < 384) {
            reinterpret_cast<float4*>(Pl)[tid] =
                reinterpret_cast<const float4*>(Pg + (size_t)c * 1536)[tid];
        }
        // ---- stage xT[i_l][b_l]: each thread 1 float4 of one b-row ----
        {
            const int ig = tid >> 6;                   // 0..7 -> i_l = ig*4..+4
            const float4 v = *reinterpret_cast<const float4*>(
                x + (size_t)(gy * 64 + lane) * WL_I + c * 32 + ig * 4);
            xT[(ig * 4 + 0) * 64 + lane] = v.x;        // bank=lane%32: 2-way, free
            xT[(ig * 4 + 1) * 64 + lane] = v.y;
            xT[(ig * 4 + 2) * 64 + lane] = v.z;
            xT[(ig * 4 + 3) * 64 + lane] = v.w;
        }
        __syncthreads();
        // ---- x chunk to registers (conflict-free: bank = lane%32) ----
        #pragma unroll
        for (int k = 0; k < 32; ++k)
            xr[k] = xT[k * 64 + lane];
        // ---- compute: 2 o x 4 quarters, params via uniform b128 broadcast ----
        WL_Q(acc0, 0, 0) WL_Q(acc0, 0, 1) WL_Q(acc0, 0, 2) WL_Q(acc0, 0, 3)
        WL_Q(acc1, 1, 0) WL_Q(acc1, 1, 1) WL_Q(acc1, 1, 2) WL_Q(acc1, 1, 3)
    }

    const int b = gy * 64 + lane;
    const int o = gx * 16 + wid * 2;
    out[(size_t)b * WL_O + o]     = acc0;              // L2 write-combines the
    out[(size_t)b * WL_O + o + 1] = acc1;              // 16-o lines per b
}

extern "C" void kernel_launch(void* const* d_in, const int* in_sizes, int n_in,
                              void* d_out, int out_size, void* d_ws, size_t ws_size,
                              hipStream_t stream) {
    const float* x           = (const float*)d_in[0];
    const float* translation = (const float*)d_in[1];
    const float* scale_raw   = (const float*)d_in[2];
    const float* weights     = (const float*)d_in[3];
    float*       out         = (float*)d_out;
    float*       P           = (float*)d_ws;           // 6.29 MB (<= 8 MB proven)

    wl_prep<<<dim3(WL_O / 64, WL_I / 16), dim3(256), 0, stream>>>(
        translation, scale_raw, weights, P);

    wl_main<<<dim3(WL_O / 16, WL_B / 64), dim3(512), 0, stream>>>(
        x, P, out);
}

// Round 11
// 104.336 us; speedup vs baseline: 1.3390x; 1.3390x over previous
//
#include <hip/hip_runtime.h>

// WaveletLinear: y[b,o] = sum_i w[o,i] * (1 - s^2) * exp(-0.5 s^2),
//   s = (x[b,i] - t[o,i]) / (A_MIN + softplus(sr[o,i]) + EPS)
// Rework: u = K*s^2, K = 0.5*log2(e); e2 = exp2(-u);
//   y = sum_i (mwk*u + w) * e2,  mwk = -w/K
//
// R16: one pipe per operand stream. R14's failure quantified the LDS unit:
// its wall (83.7us) == its LDS-pipe cycle count (195k cyc/CU); retro-fitting
// R11 shows 20.5us of LDS (x broadcasts) + ~27us VALU+trans == 47.4 wall.
// So R11's idle was LDS contention, not param L2 latency. Fix: x moves to
// the SCALAR memory path -- prep writes x^T (1MB ws), main reads each step's
// 16 b-values as one s_load_dwordx16 (wave-uniform addr via readfirstlane).
// Main loop: params->VMEM, x->SMEM, acc->VGPR, NO in-loop LDS at all.
// Geometry/math = R11 verified (lane=o, b-tile 16, 4 VALU + 1 trans/elem).
// Transpose fused into prep (576 blocks, block-uniform branch); 2 launches.
// Watch: SGPR_Count > 48 => scalarization happened (if 32, result is void).

#define WL_A_MIN 0.001f
#define WL_EPS   1e-8f

constexpr int WL_B = 512;
constexpr int WL_O = 1024;
constexpr int WL_I = 512;

// K = 0.5*log2(e); sqrt(K); 1/K; log2(e); ln(2)
#define WL_SQK  0.84932180553704583800f
#define WL_IK   1.38629436111989061883f
#define WL_L2E  1.44269504088896340736f
#define WL_LN2  0.69314718055994530942f

typedef float v2f __attribute__((ext_vector_type(2)));

struct P3 { float nti, inv, w; };          // prep-internal LDS staging

__device__ __forceinline__ float fast_exp2(float a) {
#if __has_builtin(__builtin_amdgcn_exp2f)
    return __builtin_amdgcn_exp2f(a);
#else
    return exp2f(a);
#endif
}
__device__ __forceinline__ float fast_log2(float a) {
#if __has_builtin(__builtin_amdgcn_logf)
    return __builtin_amdgcn_logf(a);
#else
    return __log2f(a);
#endif
}
__device__ __forceinline__ float fast_rcp(float a) {
#if __has_builtin(__builtin_amdgcn_rcpf)
    return __builtin_amdgcn_rcpf(a);
#else
    return 1.0f / a;
#endif
}

// Fused prep, grid = 576 x 256 thr (block-uniform branch):
//  blocks 0..511  : param precompute (verified R10 path) -> A2[i][o]={nti,inv},
//                   W1[i][o]=w  (64 o x 16 i per block)
//  blocks 512..575: x transpose -> xT[i][b] (64x64 tiles via LDS)
__global__ __launch_bounds__(256) void wl_prep(
    const float* __restrict__ x,
    const float* __restrict__ translation,
    const float* __restrict__ scale_raw,
    const float* __restrict__ weights,
    v2f* __restrict__ A2,
    float* __restrict__ W1,
    float* __restrict__ xT)
{
    __shared__ float lds_raw[64 * 65];                 // 16.6 KB, shared by both roles
    const int t   = threadIdx.x;
    const int bid = blockIdx.x;

    if (bid < 512) {
        // ---- params: o0 = (bid&15)*64, i0 = (bid>>4)*16 ----
        P3* lds = reinterpret_cast<P3*>(lds_raw);      // 16*64 P3 = 3072 floats
        const int o0 = (bid & 15) * 64;
        const int i0 = (bid >> 4) * 16;
        {
            const int o_l = t >> 2;                    // 0..63
            const int iq  = t & 3;                     // 0..3 -> 4 i each
            const size_t g = (size_t)(o0 + o_l) * WL_I + (i0 + iq * 4);
            const float4 tv = *reinterpret_cast<const float4*>(translation + g);
            const float4 sv = *reinterpret_cast<const float4*>(scale_raw   + g);
            const float4 wv = *reinterpret_cast<const float4*>(weights     + g);
            const float tt[4] = {tv.x, tv.y, tv.z, tv.w};
            const float ss[4] = {sv.x, sv.y, sv.z, sv.w};
            const float ww[4] = {wv.x, wv.y, wv.z, wv.w};
            #pragma unroll
            for (int j = 0; j < 4; ++j) {
                float ex  = fast_exp2(ss[j] * WL_L2E); // softplus via hw exp2/log2
                float sp  = fast_log2(1.0f + ex) * WL_LN2;
                float inv = fast_rcp(WL_A_MIN + sp + WL_EPS) * WL_SQK;
                P3 pv; pv.nti = -tt[j] * inv; pv.inv = inv; pv.w = ww[j];
                lds[(iq * 4 + j) * 64 + o_l] = pv;
            }
        }
        __syncthreads();
        {
            const int o_l = t & 63;
            const int r   = t >> 6;                    // 0..3 -> 4 i each
            const int o   = o0 + o_l;
            #pragma unroll
            for (int j = 0; j < 4; ++j) {
                const int i_l = r * 4 + j;
                P3 a = lds[i_l * 64 + o_l];
                A2[(size_t)(i0 + i_l) * WL_O + o] = (v2f){a.nti, a.inv};
                W1[(size_t)(i0 + i_l) * WL_O + o] = a.w;
            }
        }
    } else {
        // ---- transpose tile (ti,tj): xT[ti*64+i_l][tj*64+b'] = x[b'][i] ----
        float* tile = lds_raw;                         // [64][65]
        const int tb = bid - 512;
        const int ti = tb >> 3, tj = tb & 7;
        {
            const int b_l = t >> 2, q = t & 3;
            const float* src = x + (size_t)(tj * 64 + b_l) * WL_I + ti * 64 + q * 16;
            #pragma unroll
            for (int k = 0; k < 4; ++k) {
                const float4 v = *reinterpret_cast<const float4*>(src + k * 4);
                const int col = q * 16 + k * 4;
                tile[b_l * 65 + col + 0] = v.x;
                tile[b_l * 65 + col + 1] = v.y;
                tile[b_l * 65 + col + 2] = v.z;
                tile[b_l * 65 + col + 3] = v.w;
            }
        }
        __syncthreads();
        {
            const int i_l = t >> 2, qb = t & 3;
            float* dst = xT + (size_t)(ti * 64 + i_l) * WL_B + tj * 64 + qb * 16;
            #pragma unroll
            for (int k = 0; k < 4; ++k) {
                float4 v;
                v.x = tile[(qb * 16 + k * 4 + 0) * 65 + i_l];
                v.y = tile[(qb * 16 + k * 4 + 1) * 65 + i_l];
                v.z = tile[(qb * 16 + k * 4 + 2) * 65 + i_l];
                v.w = tile[(qb * 16 + k * 4 + 3) * 65 + i_l];
                *reinterpret_cast<float4*>(dst + k * 4) = v;
            }
        }
    }
}

// Main: grid (O/64=16, B/16=32) = 512 blocks (2/CU), 1024 thr = 16 waves.
// Wave wid = i-sixteenth (32 i); covers all 16 b via SGPR-resident x.
// Linear bid % 16 = o-block -> o-slab pinned per XCD (param L2 reuse).
__global__ __launch_bounds__(1024, 8) void wl_main(
    const float* __restrict__ xT,
    const v2f* __restrict__ A2,
    const float* __restrict__ W1,
    float* __restrict__ out)
{
    __shared__ float smem[8192];                       // 32 KB, reduce only

    const int tid  = threadIdx.x;
    const int lane = tid & 63;
    const int wid  = tid >> 6;                         // 0..15 = i-sixteenth
    const int o    = blockIdx.x * 64 + lane;
    const int b0   = blockIdx.y * 16;

    // wave-uniform wid for the scalar x path (divergence analysis can't
    // prove tid>>6 uniform; readfirstlane forces it into an SGPR)
    const int widu = __builtin_amdgcn_readfirstlane(wid);

    const v2f*   __restrict__ pA = A2 + (size_t)(wid * 32) * WL_O + o;
    const float* __restrict__ pW = W1 + (size_t)(wid * 32) * WL_O + o;
    const float* __restrict__ xs = xT + (size_t)(widu * 32) * WL_B + b0; // uniform

    float acc[16] = {0.f,0.f,0.f,0.f, 0.f,0.f,0.f,0.f,
                     0.f,0.f,0.f,0.f, 0.f,0.f,0.f,0.f};

    #pragma unroll 4
    for (int ii = 0; ii < 32; ++ii) {
        const v2f   pa = pA[(size_t)ii * WL_O];        // {nti,inv} 512B/wave VMEM
        const float w  = pW[(size_t)ii * WL_O];        // w          256B/wave VMEM
        const float mwk = w * (-WL_IK);
        const float nti = pa.x, inv = pa.y;
        const float* xrow = xs + (size_t)ii * WL_B;    // uniform -> s_load_dwordx16
        #pragma unroll
        for (int b = 0; b < 16; ++b) {
            const float s = fmaf(xrow[b], inv, nti);   // SGPR x operand
            const float u = s * s;
            const float e = fast_exp2(-u);             // trans pipe
            const float v = fmaf(mwk, u, w);
            acc[b] = fmaf(v, e, acc[b]);
        }
    }

    // ---- reduce over 16 i-waves: two phases of 8 b each (R11-verified) ----
    __syncthreads();
    #pragma unroll
    for (int k = 0; k < 8; ++k)                        // dump acc[0..7] (b_l 0..7)
        smem[(wid * 8 + k) * 64 + lane] = acc[k];      // lane-stride 4B: conflict-free
    __syncthreads();
    if (wid < 8) {                                     // wave w sums b_l = w
        float y = 0.f;
        #pragma unroll
        for (int src = 0; src < 16; ++src)
            y += smem[(src * 8 + wid) * 64 + lane];
        out[(size_t)(b0 + wid) * WL_O + o] = y;
    }
    __syncthreads();
    #pragma unroll
    for (int k = 0; k < 8; ++k)                        // dump acc[8..15] (b_l 8..15)
        smem[(wid * 8 + k) * 64 + lane] = acc[8 + k];
    __syncthreads();
    if (wid >= 8) {                                    // wave w sums b_l = w-8
        float y = 0.f;
        #pragma unroll
        for (int src = 0; src < 16; ++src)
            y += smem[(src * 8 + (wid - 8)) * 64 + lane];
        out[(size_t)(b0 + wid) * WL_O + o] = y;
    }
}

extern "C" void kernel_launch(void* const* d_in, const int* in_sizes, int n_in,
                              void* d_out, int out_size, void* d_ws, size_t ws_size,
                              hipStream_t stream) {
    const float* x           = (const float*)d_in[0];
    const float* translation = (const float*)d_in[1];
    const float* scale_raw   = (const float*)d_in[2];
    const float* weights     = (const float*)d_in[3];
    float*       out         = (float*)d_out;
    // workspace: A2 4.19MB | W1 2.10MB | xT 1.05MB  = 7.34MB
    v2f*   A2 = (v2f*)d_ws;
    float* W1 = (float*)((char*)d_ws + (size_t)WL_I * WL_O * sizeof(v2f));
    float* xT = (float*)((char*)d_ws + (size_t)WL_I * WL_O * (sizeof(v2f) + sizeof(float)));

    wl_prep<<<dim3(576), dim3(256), 0, stream>>>(
        x, translation, scale_raw, weights, A2, W1, xT);

    wl_main<<<dim3(WL_O / 64, WL_B / 16), dim3(1024), 0, stream>>>(
        xT, A2, W1, out);
}

// Round 12
// 104.313 us; speedup vs baseline: 1.3393x; 1.0002x over previous
//
#include <hip/hip_runtime.h>

// WaveletLinear: y[b,o] = sum_i w[o,i] * (1 - s^2) * exp(-0.5 s^2),
//   s = (x[b,i] - t[o,i]) / (A_MIN + softplus(sr[o,i]) + EPS)
// Rework: u = K*s^2, K = 0.5*log2(e); e2 = exp2(-u);
//   y = sum_i (mwk*u + w) * e2,  mwk = -w/K
//
// R17: break the dependency chains. Unifying diagnosis of R10/R11/R16: wall
// is invariant at 26-30 cyc per ELEMENT across completely different memory
// structures == the per-element chain latency fma->mul->exp->fma->fma
// (~30 cyc). R16's VGPR_Count=20 (acc[16]+4 temps!) proves the allocator
// serialized the 16 chains depth-first. Fix: breadth-first batches of 8 --
// all 8 s, all 8 u, all 8 exp, all 8 acc -- via fully-unrolled constant-
// index arrays (named SSA, rule-#20-safe). 8-way ILP covers the ~16 cyc
// exp latency; live set ~40-48 VGPR under the 64 cap of (1024,8).
// Everything else byte-identical to R16 (best verified: 45.4us, SMEM x path,
// zero in-loop LDS). Tells: VGPR 40-56 (if ~20, restructure failed);
// WRITE_SIZE 2048 (no scratch).

#define WL_A_MIN 0.001f
#define WL_EPS   1e-8f

constexpr int WL_B = 512;
constexpr int WL_O = 1024;
constexpr int WL_I = 512;

// K = 0.5*log2(e); sqrt(K); 1/K; log2(e); ln(2)
#define WL_SQK  0.84932180553704583800f
#define WL_IK   1.38629436111989061883f
#define WL_L2E  1.44269504088896340736f
#define WL_LN2  0.69314718055994530942f

typedef float v2f __attribute__((ext_vector_type(2)));

struct P3 { float nti, inv, w; };          // prep-internal LDS staging

__device__ __forceinline__ float fast_exp2(float a) {
#if __has_builtin(__builtin_amdgcn_exp2f)
    return __builtin_amdgcn_exp2f(a);
#else
    return exp2f(a);
#endif
}
__device__ __forceinline__ float fast_log2(float a) {
#if __has_builtin(__builtin_amdgcn_logf)
    return __builtin_amdgcn_logf(a);
#else
    return __log2f(a);
#endif
}
__device__ __forceinline__ float fast_rcp(float a) {
#if __has_builtin(__builtin_amdgcn_rcpf)
    return __builtin_amdgcn_rcpf(a);
#else
    return 1.0f / a;
#endif
}

// Fused prep (UNCHANGED from R16, verified), grid = 576 x 256 thr:
//  blocks 0..511  : param precompute -> A2[i][o]={nti,inv}, W1[i][o]=w
//  blocks 512..575: x transpose -> xT[i][b] (64x64 tiles via LDS)
__global__ __launch_bounds__(256) void wl_prep(
    const float* __restrict__ x,
    const float* __restrict__ translation,
    const float* __restrict__ scale_raw,
    const float* __restrict__ weights,
    v2f* __restrict__ A2,
    float* __restrict__ W1,
    float* __restrict__ xT)
{
    __shared__ float lds_raw[64 * 65];                 // 16.6 KB, shared by both roles
    const int t   = threadIdx.x;
    const int bid = blockIdx.x;

    if (bid < 512) {
        // ---- params: o0 = (bid&15)*64, i0 = (bid>>4)*16 ----
        P3* lds = reinterpret_cast<P3*>(lds_raw);      // 16*64 P3 = 3072 floats
        const int o0 = (bid & 15) * 64;
        const int i0 = (bid >> 4) * 16;
        {
            const int o_l = t >> 2;                    // 0..63
            const int iq  = t & 3;                     // 0..3 -> 4 i each
            const size_t g = (size_t)(o0 + o_l) * WL_I + (i0 + iq * 4);
            const float4 tv = *reinterpret_cast<const float4*>(translation + g);
            const float4 sv = *reinterpret_cast<const float4*>(scale_raw   + g);
            const float4 wv = *reinterpret_cast<const float4*>(weights     + g);
            const float tt[4] = {tv.x, tv.y, tv.z, tv.w};
            const float ss[4] = {sv.x, sv.y, sv.z, sv.w};
            const float ww[4] = {wv.x, wv.y, wv.z, wv.w};
            #pragma unroll
            for (int j = 0; j < 4; ++j) {
                float ex  = fast_exp2(ss[j] * WL_L2E); // softplus via hw exp2/log2
                float sp  = fast_log2(1.0f + ex) * WL_LN2;
                float inv = fast_rcp(WL_A_MIN + sp + WL_EPS) * WL_SQK;
                P3 pv; pv.nti = -tt[j] * inv; pv.inv = inv; pv.w = ww[j];
                lds[(iq * 4 + j) * 64 + o_l] = pv;
            }
        }
        __syncthreads();
        {
            const int o_l = t & 63;
            const int r   = t >> 6;                    // 0..3 -> 4 i each
            const int o   = o0 + o_l;
            #pragma unroll
            for (int j = 0; j < 4; ++j) {
                const int i_l = r * 4 + j;
                P3 a = lds[i_l * 64 + o_l];
                A2[(size_t)(i0 + i_l) * WL_O + o] = (v2f){a.nti, a.inv};
                W1[(size_t)(i0 + i_l) * WL_O + o] = a.w;
            }
        }
    } else {
        // ---- transpose tile (ti,tj): xT[ti*64+i_l][tj*64+b'] = x[b'][i] ----
        float* tile = lds_raw;                         // [64][65]
        const int tb = bid - 512;
        const int ti = tb >> 3, tj = tb & 7;
        {
            const int b_l = t >> 2, q = t & 3;
            const float* src = x + (size_t)(tj * 64 + b_l) * WL_I + ti * 64 + q * 16;
            #pragma unroll
            for (int k = 0; k < 4; ++k) {
                const float4 v = *reinterpret_cast<const float4*>(src + k * 4);
                const int col = q * 16 + k * 4;
                tile[b_l * 65 + col + 0] = v.x;
                tile[b_l * 65 + col + 1] = v.y;
                tile[b_l * 65 + col + 2] = v.z;
                tile[b_l * 65 + col + 3] = v.w;
            }
        }
        __syncthreads();
        {
            const int i_l = t >> 2, qb = t & 3;
            float* dst = xT + (size_t)(ti * 64 + i_l) * WL_B + tj * 64 + qb * 16;
            #pragma unroll
            for (int k = 0; k < 4; ++k) {
                float4 v;
                v.x = tile[(qb * 16 + k * 4 + 0) * 65 + i_l];
                v.y = tile[(qb * 16 + k * 4 + 1) * 65 + i_l];
                v.z = tile[(qb * 16 + k * 4 + 2) * 65 + i_l];
                v.w = tile[(qb * 16 + k * 4 + 3) * 65 + i_l];
                *reinterpret_cast<float4*>(dst + k * 4) = v;
            }
        }
    }
}

// Main: grid (O/64=16, B/16=32) = 512 blocks (2/CU), 1024 thr = 16 waves.
// Wave wid = i-sixteenth (32 i); covers all 16 b via SGPR-resident x.
__global__ __launch_bounds__(1024, 8) void wl_main(
    const float* __restrict__ xT,
    const v2f* __restrict__ A2,
    const float* __restrict__ W1,
    float* __restrict__ out)
{
    __shared__ float smem[8192];                       // 32 KB, reduce only

    const int tid  = threadIdx.x;
    const int lane = tid & 63;
    const int wid  = tid >> 6;                         // 0..15 = i-sixteenth
    const int o    = blockIdx.x * 64 + lane;
    const int b0   = blockIdx.y * 16;

    // wave-uniform wid for the scalar x path
    const int widu = __builtin_amdgcn_readfirstlane(wid);

    const v2f*   __restrict__ pA = A2 + (size_t)(wid * 32) * WL_O + o;
    const float* __restrict__ pW = W1 + (size_t)(wid * 32) * WL_O + o;
    const float* __restrict__ xs = xT + (size_t)(widu * 32) * WL_B + b0; // uniform

    float acc[16] = {0.f,0.f,0.f,0.f, 0.f,0.f,0.f,0.f,
                     0.f,0.f,0.f,0.f, 0.f,0.f,0.f,0.f};

    #pragma unroll 2
    for (int ii = 0; ii < 32; ++ii) {
        const v2f   pa = pA[(size_t)ii * WL_O];        // {nti,inv} 512B/wave VMEM
        const float w  = pW[(size_t)ii * WL_O];        // w          256B/wave VMEM
        const float mwk = w * (-WL_IK);
        const float nti = pa.x, inv = pa.y;
        const float* xrow = xs + (size_t)ii * WL_B;    // uniform -> s_load SGPR x

        // breadth-first: two batches of 8 independent chains
        #pragma unroll
        for (int h = 0; h < 2; ++h) {
            float sv[8], ev[8];
            #pragma unroll
            for (int b = 0; b < 8; ++b)                // phase 1: all 8 s
                sv[b] = fmaf(xrow[h * 8 + b], inv, nti);
            #pragma unroll
            for (int b = 0; b < 8; ++b)                // phase 2: all 8 u = s*s
                sv[b] = sv[b] * sv[b];
            #pragma unroll
            for (int b = 0; b < 8; ++b)                // phase 3: all 8 exp
                ev[b] = fast_exp2(-sv[b]);
            #pragma unroll
            for (int b = 0; b < 8; ++b)                // phase 4: all 8 acc
                acc[h * 8 + b] = fmaf(fmaf(mwk, sv[b], w), ev[b], acc[h * 8 + b]);
        }
    }

    // ---- reduce over 16 i-waves: two phases of 8 b each (verified) ----
    __syncthreads();
    #pragma unroll
    for (int k = 0; k < 8; ++k)                        // dump acc[0..7] (b_l 0..7)
        smem[(wid * 8 + k) * 64 + lane] = acc[k];      // lane-stride 4B: conflict-free
    __syncthreads();
    if (wid < 8) {                                     // wave w sums b_l = w
        float y = 0.f;
        #pragma unroll
        for (int src = 0; src < 16; ++src)
            y += smem[(src * 8 + wid) * 64 + lane];
        out[(size_t)(b0 + wid) * WL_O + o] = y;
    }
    __syncthreads();
    #pragma unroll
    for (int k = 0; k < 8; ++k)                        // dump acc[8..15] (b_l 8..15)
        smem[(wid * 8 + k) * 64 + lane] = acc[8 + k];
    __syncthreads();
    if (wid >= 8) {                                    // wave w sums b_l = w-8
        float y = 0.f;
        #pragma unroll
        for (int src = 0; src < 16; ++src)
            y += smem[(src * 8 + (wid - 8)) * 64 + lane];
        out[(size_t)(b0 + wid) * WL_O + o] = y;
    }
}

extern "C" void kernel_launch(void* const* d_in, const int* in_sizes, int n_in,
                              void* d_out, int out_size, void* d_ws, size_t ws_size,
                              hipStream_t stream) {
    const float* x           = (const float*)d_in[0];
    const float* translation = (const float*)d_in[1];
    const float* scale_raw   = (const float*)d_in[2];
    const float* weights     = (const float*)d_in[3];
    float*       out         = (float*)d_out;
    // workspace: A2 4.19MB | W1 2.10MB | xT 1.05MB  = 7.34MB
    v2f*   A2 = (v2f*)d_ws;
    float* W1 = (float*)((char*)d_ws + (size_t)WL_I * WL_O * sizeof(v2f));
    float* xT = (float*)((char*)d_ws + (size_t)WL_I * WL_O * (sizeof(v2f) + sizeof(float)));

    wl_prep<<<dim3(576), dim3(256), 0, stream>>>(
        x, translation, scale_raw, weights, A2, W1, xT);

    wl_main<<<dim3(WL_O / 64, WL_B / 16), dim3(1024), 0, stream>>>(
        xT, A2, W1, out);
}

// Round 13
// 103.191 us; speedup vs baseline: 1.3538x; 1.0109x over previous
//
#include <hip/hip_runtime.h>

// WaveletLinear: y[b,o] = sum_i w[o,i] * (1 - s^2) * exp(-0.5 s^2),
//   s = (x[b,i] - t[o,i]) / (A_MIN + softplus(sr[o,i]) + EPS)
// Rework: u = K*s^2, K = 0.5*log2(e); e2 = exp2(-u);
//   y = sum_i (mwk*u + w) * e2,  mwk = -w/K
//
// R18: discriminate issue-bound vs memory-stall-bound. Wall arithmetic now
// fits ALL rounds if v_exp_f32 = 16 cyc/wave64 (R17: 101k cyc/SIMD model vs
// 107k wall); rival model (trans unit off-port) puts floor at 27us with the
// 38% idle = one exposed ~150-200cyc L2/SMEM wait per wave-step (loads are
// JIT: zero load->use distance). This round removes the waits:
//  1. params repacked P3{nti,inv,w} -> ONE dwordx3 load/step (one vmcnt).
//  2. depth-1 pipeline in NAMED SCALARS (prologue + 31x{prefetch;compute;
//     rotate} + epilogue; no cur/nxt indexing -> R12/R13 spill excluded).
//  3. x-row prefetched identically via constant-index wave-uniform arrays
//     (SGPR-resident; rotation = s_movs, co-issued with VALU).
// Neutral result => issue-serial model confirmed => declare roofline next.
// Tells: WRITE_SIZE 2048 (no scratch), VGPR 40-56, absmax 0.0039.

#define WL_A_MIN 0.001f
#define WL_EPS   1e-8f

constexpr int WL_B = 512;
constexpr int WL_O = 1024;
constexpr int WL_I = 512;

// K = 0.5*log2(e); sqrt(K); 1/K; log2(e); ln(2)
#define WL_SQK  0.84932180553704583800f
#define WL_IK   1.38629436111989061883f
#define WL_L2E  1.44269504088896340736f
#define WL_LN2  0.69314718055994530942f

struct P3 { float nti, inv, w; };          // 12 B packed params

__device__ __forceinline__ float fast_exp2(float a) {
#if __has_builtin(__builtin_amdgcn_exp2f)
    return __builtin_amdgcn_exp2f(a);
#else
    return exp2f(a);
#endif
}
__device__ __forceinline__ float fast_log2(float a) {
#if __has_builtin(__builtin_amdgcn_logf)
    return __builtin_amdgcn_logf(a);
#else
    return __log2f(a);
#endif
}
__device__ __forceinline__ float fast_rcp(float a) {
#if __has_builtin(__builtin_amdgcn_rcpf)
    return __builtin_amdgcn_rcpf(a);
#else
    return 1.0f / a;
#endif
}

// Fused prep (R16-verified structure), grid = 576 x 256 thr:
//  blocks 0..511  : param precompute -> pT[i][o] = {nti,inv,w} (12B, coalesced)
//  blocks 512..575: x transpose -> xT[i][b] (64x64 tiles via LDS)
__global__ __launch_bounds__(256) void wl_prep(
    const float* __restrict__ x,
    const float* __restrict__ translation,
    const float* __restrict__ scale_raw,
    const float* __restrict__ weights,
    P3* __restrict__ pT,
    float* __restrict__ xT)
{
    __shared__ float lds_raw[64 * 65];                 // 16.6 KB, both roles
    const int t   = threadIdx.x;
    const int bid = blockIdx.x;

    if (bid < 512) {
        P3* lds = reinterpret_cast<P3*>(lds_raw);      // 16*64 P3
        const int o0 = (bid & 15) * 64;
        const int i0 = (bid >> 4) * 16;
        {
            const int o_l = t >> 2;                    // 0..63
            const int iq  = t & 3;                     // 0..3 -> 4 i each
            const size_t g = (size_t)(o0 + o_l) * WL_I + (i0 + iq * 4);
            const float4 tv = *reinterpret_cast<const float4*>(translation + g);
            const float4 sv = *reinterpret_cast<const float4*>(scale_raw   + g);
            const float4 wv = *reinterpret_cast<const float4*>(weights     + g);
            const float tt[4] = {tv.x, tv.y, tv.z, tv.w};
            const float ss[4] = {sv.x, sv.y, sv.z, sv.w};
            const float ww[4] = {wv.x, wv.y, wv.z, wv.w};
            #pragma unroll
            for (int j = 0; j < 4; ++j) {
                float ex  = fast_exp2(ss[j] * WL_L2E); // softplus via hw exp2/log2
                float sp  = fast_log2(1.0f + ex) * WL_LN2;
                float inv = fast_rcp(WL_A_MIN + sp + WL_EPS) * WL_SQK;
                P3 pv; pv.nti = -tt[j] * inv; pv.inv = inv; pv.w = ww[j];
                lds[(iq * 4 + j) * 64 + o_l] = pv;
            }
        }
        __syncthreads();
        {
            const int o_l = t & 63;
            const int r   = t >> 6;                    // 0..3 -> 4 i each
            const int o   = o0 + o_l;
            #pragma unroll
            for (int j = 0; j < 4; ++j) {
                const int i_l = r * 4 + j;
                pT[(size_t)(i0 + i_l) * WL_O + o] = lds[i_l * 64 + o_l];
            }
        }
    } else {
        // ---- transpose tile (ti,tj): xT[ti*64+i_l][tj*64+b'] = x[b'][i] ----
        float* tile = lds_raw;                         // [64][65]
        const int tb = bid - 512;
        const int ti = tb >> 3, tj = tb & 7;
        {
            const int b_l = t >> 2, q = t & 3;
            const float* src = x + (size_t)(tj * 64 + b_l) * WL_I + ti * 64 + q * 16;
            #pragma unroll
            for (int k = 0; k < 4; ++k) {
                const float4 v = *reinterpret_cast<const float4*>(src + k * 4);
                const int col = q * 16 + k * 4;
                tile[b_l * 65 + col + 0] = v.x;
                tile[b_l * 65 + col + 1] = v.y;
                tile[b_l * 65 + col + 2] = v.z;
                tile[b_l * 65 + col + 3] = v.w;
            }
        }
        __syncthreads();
        {
            const int i_l = t >> 2, qb = t & 3;
            float* dst = xT + (size_t)(ti * 64 + i_l) * WL_B + tj * 64 + qb * 16;
            #pragma unroll
            for (int k = 0; k < 4; ++k) {
                float4 v;
                v.x = tile[(qb * 16 + k * 4 + 0) * 65 + i_l];
                v.y = tile[(qb * 16 + k * 4 + 1) * 65 + i_l];
                v.z = tile[(qb * 16 + k * 4 + 2) * 65 + i_l];
                v.w = tile[(qb * 16 + k * 4 + 3) * 65 + i_l];
                *reinterpret_cast<float4*>(dst + k * 4) = v;
            }
        }
    }
}

// one 16-b step (breadth-first phases; inputs are named scalars + const-idx
// wave-uniform array)
__device__ __forceinline__ void wl_step(const float nti, const float inv,
                                        const float w, const float* xc,
                                        float* acc) {
    const float mwk = w * (-WL_IK);
    #pragma unroll
    for (int h = 0; h < 2; ++h) {
        float sv[8], ev[8];
        #pragma unroll
        for (int b = 0; b < 8; ++b)
            sv[b] = fmaf(xc[h * 8 + b], inv, nti);
        #pragma unroll
        for (int b = 0; b < 8; ++b)
            sv[b] = sv[b] * sv[b];
        #pragma unroll
        for (int b = 0; b < 8; ++b)
            ev[b] = fast_exp2(-sv[b]);
        #pragma unroll
        for (int b = 0; b < 8; ++b)
            acc[h * 8 + b] = fmaf(fmaf(mwk, sv[b], w), ev[b], acc[h * 8 + b]);
    }
}

// Main: grid (O/64=16, B/16=32) = 512 blocks (2/CU), 1024 thr = 16 waves.
// Wave wid = i-sixteenth (32 i); x via SGPR (wave-uniform s_loads).
__global__ __launch_bounds__(1024, 8) void wl_main(
    const float* __restrict__ xT,
    const P3* __restrict__ pT,
    float* __restrict__ out)
{
    __shared__ float smem[8192];                       // 32 KB, reduce only

    const int tid  = threadIdx.x;
    const int lane = tid & 63;
    const int wid  = tid >> 6;                         // 0..15 = i-sixteenth
    const int o    = blockIdx.x * 64 + lane;
    const int b0   = blockIdx.y * 16;

    const int widu = __builtin_amdgcn_readfirstlane(wid);

    const P3*    __restrict__ pp = pT + (size_t)(wid * 32) * WL_O + o;
    const float* __restrict__ xs = xT + (size_t)(widu * 32) * WL_B + b0;

    float acc[16] = {0.f,0.f,0.f,0.f, 0.f,0.f,0.f,0.f,
                     0.f,0.f,0.f,0.f, 0.f,0.f,0.f,0.f};

    // ---- depth-1 software pipeline, named scalars / const-idx uniforms ----
    P3 pc = pp[0];                                     // step 0 params
    float xc[16];
    #pragma unroll
    for (int b = 0; b < 16; ++b) xc[b] = xs[b];        // step 0 x (SGPR)

    for (int ii = 0; ii < 31; ++ii) {
        // prefetch step ii+1 (issue loads before compute; waits land after)
        const P3 pn = pp[(size_t)(ii + 1) * WL_O];
        float xn[16];
        #pragma unroll
        for (int b = 0; b < 16; ++b)
            xn[b] = xs[(size_t)(ii + 1) * WL_B + b];
        // compute step ii
        wl_step(pc.nti, pc.inv, pc.w, xc, acc);
        // rotate
        pc = pn;
        #pragma unroll
        for (int b = 0; b < 16; ++b) xc[b] = xn[b];
    }
    wl_step(pc.nti, pc.inv, pc.w, xc, acc);            // epilogue: step 31

    // ---- reduce over 16 i-waves: two phases of 8 b each (verified) ----
    __syncthreads();
    #pragma unroll
    for (int k = 0; k < 8; ++k)                        // dump acc[0..7]
        smem[(wid * 8 + k) * 64 + lane] = acc[k];      // lane-stride 4B: conflict-free
    __syncthreads();
    if (wid < 8) {
        float y = 0.f;
        #pragma unroll
        for (int src = 0; src < 16; ++src)
            y += smem[(src * 8 + wid) * 64 + lane];
        out[(size_t)(b0 + wid) * WL_O + o] = y;
    }
    __syncthreads();
    #pragma unroll
    for (int k = 0; k < 8; ++k)                        // dump acc[8..15]
        smem[(wid * 8 + k) * 64 + lane] = acc[8 + k];
    __syncthreads();
    if (wid >= 8) {
        float y = 0.f;
        #pragma unroll
        for (int src = 0; src < 16; ++src)
            y += smem[(src * 8 + (wid - 8)) * 64 + lane];
        out[(size_t)(b0 + wid) * WL_O + o] = y;
    }
}

extern "C" void kernel_launch(void* const* d_in, const int* in_sizes, int n_in,
                              void* d_out, int out_size, void* d_ws, size_t ws_size,
                              hipStream_t stream) {
    const float* x           = (const float*)d_in[0];
    const float* translation = (const float*)d_in[1];
    const float* scale_raw   = (const float*)d_in[2];
    const float* weights     = (const float*)d_in[3];
    float*       out         = (float*)d_out;
    // workspace: pT 6.29MB | xT 1.05MB = 7.34MB (same footprint as R16/R17)
    P3*    pT = (P3*)d_ws;
    float* xT = (float*)((char*)d_ws + (size_t)WL_I * WL_O * sizeof(P3));

    wl_prep<<<dim3(576), dim3(256), 0, stream>>>(
        x, translation, scale_raw, weights, pT, xT);

    wl_main<<<dim3(WL_O / 64, WL_B / 16), dim3(1024), 0, stream>>>(
        xT, pT, out);
}